// Round 15
// baseline (490.059 us; speedup 1.0000x reference)
//
#include <hip/hip_runtime.h>
#include <hip/hip_cooperative_groups.h>

namespace cg = cooperative_groups;

#define G_ 100
#define T_ 24
#define NSC 128
#define BATCH 8
#define NITER 40
#define NBLK (BATCH*T_)     // 192 WGs: one (batch,t) per WG
#define NTHR 512            // 8 waves -> 2 waves/SIMD
#define GMAX 15             // pass-A g's per wave

typedef unsigned long long u64;

__device__ __forceinline__ u64 gload64(const u64* p){
  return __hip_atomic_load(p, __ATOMIC_RELAXED, __HIP_MEMORY_SCOPE_AGENT);
}
__device__ __forceinline__ void gstore64(u64* p, u64 v){
  __hip_atomic_store(p, v, __ATOMIC_RELAXED, __HIP_MEMORY_SCOPE_AGENT);
}
__device__ __forceinline__ u64 pack(float v, unsigned tag){
  return ((u64)tag<<32) | (u64)__float_as_uint(v);
}
__device__ __forceinline__ float unpackv(u64 x){ return __uint_as_float((unsigned)x); }
__device__ __forceinline__ unsigned unpackt(u64 x){ return (unsigned)(x>>32); }

__device__ __forceinline__ void blockReduce2(float& a, float& b, float* sR){
#pragma unroll
  for (int off=32; off; off>>=1){ a+=__shfl_down(a,off,64); b+=__shfl_down(b,off,64); }
  const int w = threadIdx.x>>6;
  __syncthreads();
  if ((threadIdx.x&63)==0){ sR[w]=a; sR[8+w]=b; }
  __syncthreads();
  a=0.f; b=0.f;
#pragma unroll
  for (int i=0;i<8;++i){ a+=sR[i]; b+=sR[8+i]; }
}

__global__ __launch_bounds__(NTHR, 1) void dro_kernel(
    const float* __restrict__ forecast, const float* __restrict__ omega,
    const float* __restrict__ om_min, const float* __restrict__ om_max,
    const float* __restrict__ eps_in, const float* __restrict__ pmin_g,
    const float* __restrict__ pmax_g, const float* __restrict__ bG,
    const float* __restrict__ cG, float* __restrict__ out, float* __restrict__ ws)
{
  constexpr float LR=2e-4f, VOLL=1000.f, VOSP=50.f, TWO_RHO=20.f, INVN=1.f/128.f;
  const int blk=blockIdx.x;
  const int b=blk&7;            // round-robin XCD: batch stays XCD-affine
  const int t_own=blk>>3;
  const int tid=threadIdx.x, wave=tid>>6, lane=tid&63;
  // pass-A g ownership: wave1 exempt (pass B); wave0 light (weights straggler):
  // wave0:10, waves2-7:15 each = 100.
  int gbase, gcnt;
  if      (wave==0){ gbase=0;  gcnt=10; }
  else if (wave==1){ gbase=0;  gcnt=0;  }
  else             { gbase=10+(wave-2)*15; gcnt=15; }
  const bool pA = (wave!=1);

  __shared__ float sRu[2][G_], sRd[2][G_];   // dbuf: passA reads cur, passB writes nxt
  __shared__ float sP[G_];
  __shared__ float sAccU[G_], sAccD[G_];
  __shared__ float sB[G_], sPmin[G_], sPmax[G_], sC[G_];
  __shared__ float sLS[NSC], sSP[NSC], sOm[NSC];
  __shared__ float sGQ[NSC], sR220[NSC];
  __shared__ float sQn[NSC], sDM[NSC], sDm[NSC], sS2[NSC];
  __shared__ float sQp[NSC*9], sSp[NSC*9];   // [n][wave] stride 9; column 1 fixed 0
  __shared__ float sQnP[NTHR];
  __shared__ float sRed[40];
  __shared__ float sScal[12];  // 8,9: S1s,S2s ; epilogue: 2=Qmax 3=Qmin 4=gamma

  u64* W = (u64*)ws;
  u64* QNP = W;                       // [3][8][24][128]
  u64* PP  = W + 73728;               // [3][8][24][128] (first 100 used)
  u64* QS  = W + 147456;              // [3][8][24][16]  (Qmax@0, Qmin@1)
  u64* GAM = W + 156672;              // [3][8][16]
  u64* ST1 = W + 157056;              // [8][24][16]
  u64* FLG = W + 160128;              // [8][24][16]  per-slice epoch flag (128B apart)

  const float epsv  = eps_in[b];
  const float omaxT = om_max[b*T_ + t_own];
  const float ominT = om_min[b*T_ + t_own];
  const float fctT  = forecast[b*T_ + t_own];
  const u64* flB   = FLG + b*T_*16;
  u64* myFlag      = FLG + (b*T_ + t_own)*16;

  // register-resident d_up/d_dn: lane holds n=lane (A) and n=lane+64 (B)
  float duA[GMAX], duB[GMAX], ddA[GMAX], ddB[GMAX];
  // wave1-resident pass-B state (2 g/lane: g=lane, g=lane+64 for lane<36)
  float duMr[2]={0.f,0.f}, ddMr[2]={0.f,0.f}, dumr[2]={0.f,0.f}, ddmr[2]={0.f,0.f};
  float lsm=0.f, spm=0.f, lsn=0.f, spn=0.f;     // wave1-lane0: LSM,SPM,LSm,SPm
  float r3reg=0.f, r4reg=0.f, rPreg=0.f;        // wave1-lane0

  // ---------------- init ----------------
  if (tid<G_){
    sB[tid]=bG[tid]; sPmin[tid]=pmin_g[tid]; sPmax[tid]=pmax_g[tid]; sC[tid]=cG[tid];
    sRu[0][tid]=0.f; sRd[0][tid]=0.f;
    sAccU[tid]=0.f; sAccD[tid]=0.f;
  }
  if (tid<NSC){
    const int nn=tid;
    sLS[nn]=0.f; sSP[nn]=0.f; sS2[nn]=0.f;
    sOm[nn]=omega[(b*NSC+nn)*T_+t_own];
    float dM=0.f,dm=0.f;
    for (int t=0;t<T_;++t){
      float o=omega[(b*NSC+nn)*T_+t];
      dM+=om_max[b*T_+t]-o; dm+=o-om_min[b*T_+t];
    }
    sDM[nn]=dM; sDm[nn]=dm;
    sQp[nn*9+1]=0.f; sSp[nn*9+1]=0.f;   // wave1 pass-A column: permanently zero
  }
  __syncthreads();
#pragma unroll
  for (int j=0;j<GMAX;++j){ duA[j]=0.f; duB[j]=0.f; ddA[j]=0.f; ddB[j]=0.f; }
  {
    float p0=0.f;
    if (tid<G_){
      p0=0.5f*(sPmin[tid]+sPmax[tid]);
      sP[tid]=p0;
      gstore64(&PP[b*3072 + t_own*128 + tid], pack(p0,1u));
    }
    if (tid<NSC) gstore64(&QNP[b*3072 + t_own*128 + tid], pack(0.f,1u));
    if (tid<2)   gstore64(&QS[(b*T_ + t_own)*16 + tid], pack(0.f,1u));
    if (t_own==0 && tid==0) gstore64(&GAM[b*16], pack(0.f,1u));
    float rp=p0, dum0=0.f;
    blockReduce2(rp,dum0,sRed);
    r3reg=-omaxT; r4reg=-ominT; rPreg=rp-fctT;
  }
  __builtin_amdgcn_s_waitcnt(0);   // drain own init data stores
  __syncthreads();
  if (tid==0) gstore64(myFlag, 1ull);   // epoch-1 flag covers this slice's init data

  for (int k=0;k<=NITER;++k){
    const unsigned tg2 = (unsigned)(k+2);
    const u64 ftg = (u64)(k+1);
    const int rb = k%3, wb = (k+1)%3;
    const int kb = k&1, nbuf = kb^1;
    float* sRuC = sRu[kb];  float* sRdC = sRd[kb];
    float* sRuN = sRu[nbuf]; float* sRdN = sRd[nbuf];
    const u64* qnpR = QNP + rb*24576 + b*3072;
    const u64* ppR  = PP  + rb*24576 + b*3072;
    const u64* qsR  = QS  + (rb*BATCH + b)*T_*16;
    const u64* gamR = GAM + (rb*BATCH + b)*16;
    u64* qnpW = QNP + wb*24576 + b*3072 + t_own*128;
    u64* ppW  = PP  + wb*24576 + b*3072 + t_own*128;
    u64* qsW  = QS  + (wb*BATCH + b)*T_*16 + t_own*16;
    u64* gamW = GAM + (wb*BATCH + b)*16;

    // ---- flag wait: wave0 polls 24 per-slice flags (tiny poll traffic) ----
    if (tid < 64){
      for (;;){
        u64 f = (lane < T_) ? gload64(&flB[lane*16]) : ftg;
        if (__ballot(f < ftg) == 0ull) break;
        __builtin_amdgcn_s_sleep(1);
      }
    }
    __syncthreads();   // barrier F: all slices' epoch-(k+1) data now LLC-visible

    // ---- load-once consume (no tag spins, no re-issue) ----
    const int n = tid&127, sb0 = (tid>>7)*6;
    const bool w0 = (wave==0), w1 = (wave==1), hasG1 = w1 && (lane<36);
    u64 xq[6];
#pragma unroll
    for (int s=0;s<6;++s) xq[s]=gload64(&qnpR[(sb0+s)*128+n]);
    u64 xm0=0,xm1=0,xp0=0,xp1=0,xs0=0,xs1=0,xg=0;
    if (w1){
      if (t_own>0){
        xm0=gload64(&ppR[(t_own-1)*128+lane]);
        if (hasG1) xm1=gload64(&ppR[(t_own-1)*128+lane+64]);
      }
      if (t_own<T_-1){
        xp0=gload64(&ppR[(t_own+1)*128+lane]);
        if (hasG1) xp1=gload64(&ppR[(t_own+1)*128+lane+64]);
      }
    } else if (w0){
      if (lane<T_){ xs0=gload64(&qsR[lane*16]); xs1=gload64(&qsR[lane*16+1]); }
      xg=gload64(gamR);
    }
    sQnP[tid]=unpackv(xq[0])+unpackv(xq[1])+unpackv(xq[2])
             +unpackv(xq[3])+unpackv(xq[4])+unpackv(xq[5]);
    float Qmax=unpackv(xs0), Qmin=unpackv(xs1);   // wave0 lanes>=24 hold 0
    const float gamma=unpackv(xg);                // wave0
    __syncthreads();   // barrier A: sQnP published

    if (k==NITER){  // ---------------- final: phi + outputs ----------------
      if (w0){
#pragma unroll
        for (int off=32; off; off>>=1){ Qmax+=__shfl_xor(Qmax,off,64); Qmin+=__shfl_xor(Qmin,off,64); }
        if (lane==0){ sScal[2]=Qmax; sScal[3]=Qmin; sScal[4]=gamma; }
      }
      __syncthreads();
      const float Qm=sScal[2], Qn2=sScal[3], gam=sScal[4];
      if (tid<NSC){
        const float qsum=sQnP[tid]+sQnP[tid+128]+sQnP[tid+256]+sQnP[tid+384];
        const float ph=fmaxf(qsum,fmaxf(Qm-gam*sDM[tid],Qn2-gam*sDm[tid]));
        sQn[tid]=ph;
        if (t_own==0) out[76800 + b*NSC + tid]=ph;
      }
      float st=0.f, dum0=0.f;
      if (tid<G_){
        const int g=tid;
        const float Pv=sP[g];
        const float costv=sB[g]*Pv+sC[g];
        st=costv + 0.05f*sB[g]*sRuC[g] + 0.02f*sB[g]*sRdC[g];
        const int o=b*2400 + g*T_ + t_own;
        out[o]=Pv;
        out[19200+o]=sRuC[g];
        out[38400+o]=sRdC[g];
        out[57600+o]=costv;
      }
      blockReduce2(st,dum0,sRed);
      if (tid==0) gstore64(&ST1[(b*T_+t_own)*16], pack(st,99u));
      if (t_own==0){
        if (tid==0) out[77824+b]=gam;
        float s1=0.f;
        if (tid<64){
          u64 xs = (lane<T_)? gload64(&ST1[(b*T_+lane)*16]) : pack(0.f,99u);
          while (unpackt(xs)!=99u){ __builtin_amdgcn_s_sleep(1); xs=gload64(&ST1[(b*T_+lane)*16]); }
          s1=unpackv(xs);
        }
        float pm=(tid<NSC)? sQn[tid] : 0.f;
        blockReduce2(pm,s1,sRed);
        if (tid==0) out[77832+b] = s1 + pm*INVN + epsv*gam;
      }
      break;
    }

    // ---- wave0: butterfly + weights + LS/SP + S-sums + early gamma ----
    if (w0){
#pragma unroll
      for (int off=32; off; off>>=1){ Qmax+=__shfl_xor(Qmax,off,64); Qmin+=__shfl_xor(Qmin,off,64); }
      float g1l=0.f,g2l=0.f,sgl=0.f;
#pragma unroll
      for (int h=0;h<2;++h){
        const int nn=lane+h*64;
        const float Qn=sQnP[nn]+sQnP[nn+128]+sQnP[nn+256]+sQnP[nn+384];
        const float m1=Qmax-gamma*sDM[nn], m2=Qmin-gamma*sDm[nn];
        const float inner=fmaxf(m1,m2), ph=fmaxf(Qn,inner);
        const float gQn=(Qn==ph?1.f:0.f)/((inner==ph)?2.f:1.f);
        const float gIn=(inner==ph?1.f:0.f)/((Qn==ph)?2.f:1.f);
        const float gm1=gIn*(m1==inner?1.f:0.f)/((m2==inner)?2.f:1.f);
        const float gm2=gIn*(m2==inner?1.f:0.f)/((m1==inner)?2.f:1.f);
        const float gq=gQn*INVN;
        sGQ[nn]=gq;
        g1l+=gm1; g2l+=gm2; sgl+=gm1*sDM[nn]+gm2*sDm[nn];
        const float r2=sS2[nn]+sLS[nn]-sSP[nn]-sOm[nn];
        const float r220=TWO_RHO*r2;
        sR220[nn]=r220;
        sLS[nn]=fmaxf(sLS[nn]-LR*(gq*VOLL+r220),0.f);
        sSP[nn]=fmaxf(sSP[nn]-LR*(gq*VOSP-r220),0.f);
      }
#pragma unroll
      for (int off=32; off; off>>=1){
        g1l+=__shfl_xor(g1l,off,64); g2l+=__shfl_xor(g2l,off,64); sgl+=__shfl_xor(sgl,off,64);
      }
      if (lane==0){ sScal[8]=g1l; sScal[9]=g2l; }
      if (t_own==0 && lane==0)
        gstore64(gamW, pack(fmaxf(gamma-LR*(epsv-INVN*sgl),0.f), tg2));
    }
    __syncthreads();   // barrier B

    // ---- pass A (waves 0,2-7) CONCURRENT WITH pass B + qs publish (wave1) ----
    if (pA){
      const float gqA=sGQ[lane],    r220A=sR220[lane];
      const float gqB=sGQ[lane+64], r220B=sR220[lane+64];
      float qvA=0.f,qvB=0.f,svA=0.f,svB=0.f;
#pragma unroll
      for (int j=0;j<GMAX;++j){
        if (j<gcnt){
          const int g=gbase+j;
          const float bg=sB[g];
          const float rtu=2.f*bg, rtd=0.5f*bg;
          const float ru=sRuC[g], rd=sRdC[g];
          const float r7A=fmaxf(duA[j]-ru,0.f), r8A=fmaxf(ddA[j]-rd,0.f);
          const float r7B=fmaxf(duB[j]-ru,0.f), r8B=fmaxf(ddB[j]-rd,0.f);
          duA[j]=fmaxf(duA[j]-LR*(gqA*rtu+(r220A+TWO_RHO*r7A)),0.f);
          ddA[j]=fmaxf(ddA[j]-LR*(gqA*rtd+(TWO_RHO*r8A-r220A)),0.f);
          duB[j]=fmaxf(duB[j]-LR*(gqB*rtu+(r220B+TWO_RHO*r7B)),0.f);
          ddB[j]=fmaxf(ddB[j]-LR*(gqB*rtd+(TWO_RHO*r8B-r220B)),0.f);
          qvA+=rtu*duA[j]+rtd*ddA[j];  svA+=duA[j]-ddA[j];
          qvB+=rtu*duB[j]+rtd*ddB[j];  svB+=duB[j]-ddB[j];
        }
      }
      sQp[lane*9+wave]=qvA;      sSp[lane*9+wave]=svA;
      sQp[(lane+64)*9+wave]=qvB; sSp[(lane+64)*9+wave]=svB;
    } else {
      // wave1: pass B (deps: consume + barrier B only — NOT pass A)
      const float r3=__shfl(r3reg,0,64), r4=__shfl(r4reg,0,64), rP=__shfl(rPreg,0,64);
      const float S1s=sScal[8], S2s=sScal[9];
      float pQx=0.f,pQn2=0.f,pr3=0.f,pr4=0.f,pP=0.f;
#pragma unroll
      for (int i=0;i<2;++i){
        if (i==0 || hasG1){
          const int g = lane + i*64;
          const float rupS=sAccU[g], rdnS=sAccD[g];
          const float Pold=sP[g], ru=sRuC[g], rd=sRdC[g];
          const float duMo=duMr[i], ddMo=ddMr[i], dumo=dumr[i], ddmo=ddmr[i];
          const float r5 =fmaxf(Pold+ru-sPmax[g],0.f);
          const float r6 =fmaxf(sPmin[g]-Pold+rd,0.f);
          const float r9 =fmaxf(duMo-ru,0.f), r10=fmaxf(ddMo-rd,0.f);
          const float r11=fmaxf(dumo-ru,0.f), r12=fmaxf(ddmo-rd,0.f);
          const float rampg=sPmax[g];
          float gP=sB[g]+TWO_RHO*(rP+r5-r6);
          if (t_own>0){
            const float dp=Pold-unpackv(i==0?xm0:xm1);
            gP+=TWO_RHO*fmaxf(fabsf(dp)-rampg,0.f)*(dp>=0.f?1.f:-1.f);
          }
          if (t_own<T_-1){
            const float dq=unpackv(i==0?xp0:xp1)-Pold;
            gP-=TWO_RHO*fmaxf(fabsf(dq)-rampg,0.f)*(dq>=0.f?1.f:-1.f);
          }
          const float Pn=fminf(fmaxf(Pold-LR*gP,sPmin[g]),sPmax[g]);
          sP[g]=Pn; gstore64(&ppW[g], pack(Pn,tg2));
          const float rtuB=2.f*sB[g], rtdB=0.5f*sB[g];
          sRuN[g]=fmaxf(ru-LR*(0.05f*sB[g]+TWO_RHO*(r5-rupS-r9-r11)),0.f);
          sRdN[g]=fmaxf(rd-LR*(0.02f*sB[g]+TWO_RHO*(r6-rdnS-r10-r12)),0.f);
          const float duMn=fmaxf(duMo-LR*(INVN*S1s*rtuB+TWO_RHO*( r3+r9 )),0.f);
          const float ddMn=fmaxf(ddMo-LR*(INVN*S1s*rtdB+TWO_RHO*(-r3+r10)),0.f);
          const float dumn=fmaxf(dumo-LR*(INVN*S2s*rtuB+TWO_RHO*( r4+r11)),0.f);
          const float ddmn=fmaxf(ddmo-LR*(INVN*S2s*rtdB+TWO_RHO*(-r4+r12)),0.f);
          duMr[i]=duMn; ddMr[i]=ddMn; dumr[i]=dumn; ddmr[i]=ddmn;
          pQx+=rtuB*duMn+rtdB*ddMn; pQn2+=rtuB*dumn+rtdB*ddmn;
          pr3+=duMn-ddMn; pr4+=dumn-ddmn; pP+=Pn;
        }
      }
#pragma unroll
      for (int off=32; off; off>>=1){
        pQx+=__shfl_down(pQx,off,64);  pQn2+=__shfl_down(pQn2,off,64);
        pr3+=__shfl_down(pr3,off,64);  pr4+=__shfl_down(pr4,off,64);
        pP +=__shfl_down(pP,off,64);
      }
      if (lane==0){
        const float LSMn=fmaxf(lsm-LR*(INVN*S1s*VOLL+TWO_RHO*r3),0.f);
        const float SPMn=fmaxf(spm-LR*(INVN*S1s*VOSP-TWO_RHO*r3),0.f);
        const float LSmn=fmaxf(lsn-LR*(INVN*S2s*VOLL+TWO_RHO*r4),0.f);
        const float SPmn=fmaxf(spn-LR*(INVN*S2s*VOSP-TWO_RHO*r4),0.f);
        lsm=LSMn; spm=SPMn; lsn=LSmn; spn=SPmn;
        gstore64(&qsW[0], pack(pQx + VOLL*LSMn + VOSP*SPMn, tg2));   // qs lands early
        gstore64(&qsW[1], pack(pQn2 + VOLL*LSmn + VOSP*SPmn, tg2));
        r3reg=pr3 + LSMn - SPMn - omaxT;
        r4reg=pr4 + LSmn - SPmn - ominT;
        rPreg=pP - fctT;
      }
    }
    __syncthreads();   // barrier C

    // ---- combine (waves 4-5) -> qnp stores ----
    if (tid>=256 && tid<384){
      const int nn=tid-256;
      float q=0.f,s=0.f;
#pragma unroll
      for (int w=0;w<8;++w){ q+=sQp[nn*9+w]; s+=sSp[nn*9+w]; }
      sS2[nn]=s;
      q += VOLL*sLS[nn]+VOSP*sSP[nn];
      gstore64(&qnpW[nn], pack(q,tg2));
    }

    // ---- publish: per-wave drain -> barrier D -> per-slice flag ----
    __builtin_amdgcn_s_waitcnt(0);
    __syncthreads();   // barrier D: all slice data (qnp,pp,qs,gam) drained to LLC
    if (tid==0) gstore64(myFlag, (u64)(k+2));

    // ---- shadow precompute (slack side, hidden in next flag wait) ----
    if (pA){
#pragma unroll
      for (int j=0;j<GMAX;++j){
        if (j<gcnt){
          const int g=gbase+j;
          const float ru=sRuN[g], rd=sRdN[g];   // new Ru/Rd (pass B done at barrier C)
          float aU=fmaxf(duA[j]-ru,0.f)+fmaxf(duB[j]-ru,0.f);
          float aD=fmaxf(ddA[j]-rd,0.f)+fmaxf(ddB[j]-rd,0.f);
#pragma unroll
          for (int off=32; off; off>>=1){ aU+=__shfl_xor(aU,off,64); aD+=__shfl_xor(aD,off,64); }
          if (lane==0){ sAccU[g]=aU; sAccD[g]=aD; }
        }
      }
    }
  }
}

extern "C" void kernel_launch(void* const* d_in, const int* in_sizes, int n_in,
                              void* d_out, int out_size, void* d_ws, size_t ws_size,
                              hipStream_t stream) {
  const float* forecast = (const float*)d_in[0];
  const float* omega    = (const float*)d_in[1];
  const float* omin     = (const float*)d_in[2];
  const float* omax     = (const float*)d_in[3];
  const float* eps      = (const float*)d_in[4];
  const float* pmin     = (const float*)d_in[5];
  const float* pmax     = (const float*)d_in[6];
  const float* bG       = (const float*)d_in[7];
  const float* cG       = (const float*)d_in[8];
  float* out = (float*)d_out;
  float* ws  = (float*)d_ws;
  void* args[] = { &forecast, &omega, &omin, &omax, &eps, &pmin, &pmax, &bG, &cG, &out, &ws };
  hipLaunchCooperativeKernel((const void*)dro_kernel, dim3(NBLK), dim3(NTHR),
                             args, 0, stream);
}

// Round 16
// 446.762 us; speedup vs baseline: 1.0969x; 1.0969x over previous
//
#include <hip/hip_runtime.h>
#include <hip/hip_cooperative_groups.h>

namespace cg = cooperative_groups;

#define G_ 100
#define T_ 24
#define NSC 128
#define BATCH 8
#define NITER 40
#define NBLK (BATCH*T_)     // 192 WGs: one (batch,t) per WG
#define NTHR 512            // 8 waves -> 2 waves/SIMD
#define GMAX 15             // pass-A g's per wave (7 waves cover 100 g)

typedef unsigned long long u64;

// (tag<<32 | float) pairs via relaxed agent-scope 8B atomics (sc1, LLC-direct).
// Consumers spin on tags; producers never fence. Depth-3 buffers, monotonic tags.
__device__ __forceinline__ u64 gload64(const u64* p){
  return __hip_atomic_load(p, __ATOMIC_RELAXED, __HIP_MEMORY_SCOPE_AGENT);
}
__device__ __forceinline__ void gstore64(u64* p, u64 v){
  __hip_atomic_store(p, v, __ATOMIC_RELAXED, __HIP_MEMORY_SCOPE_AGENT);
}
__device__ __forceinline__ u64 pack(float v, unsigned tag){
  return ((u64)tag<<32) | (u64)__float_as_uint(v);
}
__device__ __forceinline__ float unpackv(u64 x){ return __uint_as_float((unsigned)x); }
__device__ __forceinline__ unsigned unpackt(u64 x){ return (unsigned)(x>>32); }

// full-block reduce (init/epilogue only)
__device__ __forceinline__ void blockReduce2(float& a, float& b, float* sR){
#pragma unroll
  for (int off=32; off; off>>=1){ a+=__shfl_down(a,off,64); b+=__shfl_down(b,off,64); }
  const int w = threadIdx.x>>6;
  __syncthreads();
  if ((threadIdx.x&63)==0){ sR[w]=a; sR[8+w]=b; }
  __syncthreads();
  a=0.f; b=0.f;
#pragma unroll
  for (int i=0;i<8;++i){ a+=sR[i]; b+=sR[8+i]; }
}

__global__ __launch_bounds__(NTHR, 1) void dro_kernel(
    const float* __restrict__ forecast, const float* __restrict__ omega,
    const float* __restrict__ om_min, const float* __restrict__ om_max,
    const float* __restrict__ eps_in, const float* __restrict__ pmin_g,
    const float* __restrict__ pmax_g, const float* __restrict__ bG,
    const float* __restrict__ cG, float* __restrict__ out, float* __restrict__ ws)
{
  constexpr float LR=2e-4f, VOLL=1000.f, VOSP=50.f, TWO_RHO=20.f, INVN=1.f/128.f;
  const int blk=blockIdx.x;
  const int b=blk&7;            // round-robin XCD: batch stays XCD-affine
  const int t_own=blk>>3;
  const int tid=threadIdx.x, wave=tid>>6, lane=tid&63;
  // pass-A g ownership: wave1 is EXEMPT (dedicated pass-B wave).
  // waves {0,2,3,4,5,6,7} own {14,15,15,14,14,14,14} g's = 100.
  int gbase, gcnt;
  if      (wave==0){ gbase=0;  gcnt=14; }
  else if (wave==1){ gbase=0;  gcnt=0;  }
  else if (wave==2){ gbase=14; gcnt=15; }
  else if (wave==3){ gbase=29; gcnt=15; }
  else             { gbase=44+(wave-4)*14; gcnt=14; }
  const bool pA = (wave!=1);

  __shared__ float sRu[2][G_], sRd[2][G_];   // double-buffered: passA reads cur, passB writes nxt
  __shared__ float sP[G_];                   // wave1-only during loop; epilogue reads
  __shared__ float sAccU[G_], sAccD[G_];
  __shared__ float sB[G_], sPmin[G_], sPmax[G_], sC[G_];
  __shared__ float sLS[NSC], sSP[NSC], sOm[NSC];
  __shared__ float sGQ[NSC], sR220[NSC];
  __shared__ float sQn[NSC], sDM[NSC], sDm[NSC], sS2[NSC];
  __shared__ float sQp[NSC*9], sSp[NSC*9];   // [n][wave] stride 9; column 1 fixed 0
  __shared__ float sQnP[NTHR];
  __shared__ float sRed[40];
  __shared__ float sScal[12];  // 8,9: S1s,S2s ; epilogue: 2=Qmax 3=Qmin 4=gamma

  u64* W = (u64*)ws;
  u64* QNP = W;                       // [3][8][24][128]
  u64* PP  = W + 73728;               // [3][8][24][128] (first 100 used)
  u64* QS  = W + 147456;              // [3][8][24][16]  (Qmax@0, Qmin@1)
  u64* GAM = W + 156672;              // [3][8][16]
  u64* ST1 = W + 157056;              // [8][24][16]

  const float epsv  = eps_in[b];
  const float omaxT = om_max[b*T_ + t_own];
  const float ominT = om_min[b*T_ + t_own];
  const float fctT  = forecast[b*T_ + t_own];

  // register-resident d_up/d_dn: lane holds n=lane (A) and n=lane+64 (B)
  float duA[GMAX], duB[GMAX], ddA[GMAX], ddB[GMAX];
  // wave1-resident pass-B state (2 g/lane: g=lane, g=lane+64 for lane<36)
  float duMr[2]={0.f,0.f}, ddMr[2]={0.f,0.f}, dumr[2]={0.f,0.f}, ddmr[2]={0.f,0.f};
  float lsm=0.f, spm=0.f, lsn=0.f, spn=0.f;     // wave1-lane0: LSM,SPM,LSm,SPm
  float r3reg=0.f, r4reg=0.f, rPreg=0.f;        // wave1-lane0

  // ---------------- init ----------------
  if (tid<G_){
    sB[tid]=bG[tid]; sPmin[tid]=pmin_g[tid]; sPmax[tid]=pmax_g[tid]; sC[tid]=cG[tid];
    sRu[0][tid]=0.f; sRd[0][tid]=0.f;
    sAccU[tid]=0.f; sAccD[tid]=0.f;
  }
  if (tid<NSC){
    const int nn=tid;
    sLS[nn]=0.f; sSP[nn]=0.f; sS2[nn]=0.f;
    sOm[nn]=omega[(b*NSC+nn)*T_+t_own];
    float dM=0.f,dm=0.f;
    for (int t=0;t<T_;++t){
      float o=omega[(b*NSC+nn)*T_+t];
      dM+=om_max[b*T_+t]-o; dm+=o-om_min[b*T_+t];
    }
    sDM[nn]=dM; sDm[nn]=dm;
    sQp[nn*9+1]=0.f; sSp[nn*9+1]=0.f;   // wave1 pass-A column: permanently zero
  }
  __syncthreads();
#pragma unroll
  for (int j=0;j<GMAX;++j){ duA[j]=0.f; duB[j]=0.f; ddA[j]=0.f; ddB[j]=0.f; }
  {
    float p0=0.f;
    if (tid<G_){
      p0=0.5f*(sPmin[tid]+sPmax[tid]);
      sP[tid]=p0;
      gstore64(&PP[b*3072 + t_own*128 + tid], pack(p0,1u));
    }
    if (tid<NSC) gstore64(&QNP[b*3072 + t_own*128 + tid], pack(0.f,1u));
    if (tid<2)   gstore64(&QS[(b*T_ + t_own)*16 + tid], pack(0.f,1u));
    if (t_own==0 && tid==0) gstore64(&GAM[b*16], pack(0.f,1u));
    float rp=p0, dum0=0.f;
    blockReduce2(rp,dum0,sRed);
    r3reg=-omaxT; r4reg=-ominT; rPreg=rp-fctT;   // wave1-lane0's copies are live
  }
  __syncthreads();

  for (int k=0;k<=NITER;++k){
    const unsigned tg  = (unsigned)(k+1);
    const unsigned tg2 = (unsigned)(k+2);
    const int rb = k%3, wb = (k+1)%3;
    const int kb = k&1, nbuf = kb^1;
    float* sRuC = sRu[kb];  float* sRdC = sRd[kb];
    float* sRuN = sRu[nbuf]; float* sRdN = sRd[nbuf];
    const u64* qnpR = QNP + rb*24576 + b*3072;
    const u64* ppR  = PP  + rb*24576 + b*3072;
    const u64* qsR  = QS  + (rb*BATCH + b)*T_*16;
    const u64* gamR = GAM + (rb*BATCH + b)*16;
    u64* qnpW = QNP + wb*24576 + b*3072 + t_own*128;
    u64* ppW  = PP  + wb*24576 + b*3072 + t_own*128;
    u64* qsW  = QS  + (wb*BATCH + b)*T_*16 + t_own*16;
    u64* gamW = GAM + (wb*BATCH + b)*16;

    // ---- consume: pre-issue, then ONE unified re-issue spin ----
    const int n = tid&127, sb0 = (tid>>7)*6;
    const bool w0 = (wave==0), w1 = (wave==1), hasG1 = w1 && (lane<36);
    u64 xq[6];
#pragma unroll
    for (int s=0;s<6;++s) xq[s]=gload64(&qnpR[(sb0+s)*128+n]);
    u64 xm0=0,xm1=0,xp0=0,xp1=0,xs0=0,xs1=0,xg=0;
    if (w1){
      if (t_own>0){
        xm0=gload64(&ppR[(t_own-1)*128+lane]);
        if (hasG1) xm1=gload64(&ppR[(t_own-1)*128+lane+64]);
      }
      if (t_own<T_-1){
        xp0=gload64(&ppR[(t_own+1)*128+lane]);
        if (hasG1) xp1=gload64(&ppR[(t_own+1)*128+lane+64]);
      }
    } else if (w0){
      if (lane<T_){ xs0=gload64(&qsR[lane*16]); xs1=gload64(&qsR[lane*16+1]); }
      xg=gload64(gamR);
    }
    for (;;){
      bool pend=false;
#pragma unroll
      for (int s=0;s<6;++s)
        if (unpackt(xq[s])!=tg){ xq[s]=gload64(&qnpR[(sb0+s)*128+n]); pend=true; }
      if (w1){
        if (t_own>0){
          if (unpackt(xm0)!=tg){ xm0=gload64(&ppR[(t_own-1)*128+lane]); pend=true; }
          if (hasG1 && unpackt(xm1)!=tg){ xm1=gload64(&ppR[(t_own-1)*128+lane+64]); pend=true; }
        }
        if (t_own<T_-1){
          if (unpackt(xp0)!=tg){ xp0=gload64(&ppR[(t_own+1)*128+lane]); pend=true; }
          if (hasG1 && unpackt(xp1)!=tg){ xp1=gload64(&ppR[(t_own+1)*128+lane+64]); pend=true; }
        }
      } else if (w0){
        if (lane<T_){
          if (unpackt(xs0)!=tg){ xs0=gload64(&qsR[lane*16]);   pend=true; }
          if (unpackt(xs1)!=tg){ xs1=gload64(&qsR[lane*16+1]); pend=true; }
        }
        if (unpackt(xg)!=tg){ xg=gload64(gamR); pend=true; }
      }
      if (!pend) break;
      __builtin_amdgcn_s_sleep(1);
    }
    sQnP[tid]=unpackv(xq[0])+unpackv(xq[1])+unpackv(xq[2])
             +unpackv(xq[3])+unpackv(xq[4])+unpackv(xq[5]);
    float Qmax=unpackv(xs0), Qmin=unpackv(xs1);   // wave0 lanes>=24 hold 0
    const float gamma=unpackv(xg);                // wave0
    __syncthreads();   // barrier A

    if (k==NITER){  // ---------------- final: phi + outputs ----------------
      if (w0){
#pragma unroll
        for (int off=32; off; off>>=1){ Qmax+=__shfl_xor(Qmax,off,64); Qmin+=__shfl_xor(Qmin,off,64); }
        if (lane==0){ sScal[2]=Qmax; sScal[3]=Qmin; sScal[4]=gamma; }
      }
      __syncthreads();
      const float Qm=sScal[2], Qn2=sScal[3], gam=sScal[4];
      if (tid<NSC){
        const float qsum=sQnP[tid]+sQnP[tid+128]+sQnP[tid+256]+sQnP[tid+384];
        const float ph=fmaxf(qsum,fmaxf(Qm-gam*sDM[tid],Qn2-gam*sDm[tid]));
        sQn[tid]=ph;
        if (t_own==0) out[76800 + b*NSC + tid]=ph;
      }
      float st=0.f, dum0=0.f;
      if (tid<G_){
        const int g=tid;
        const float Pv=sP[g];
        const float costv=sB[g]*Pv+sC[g];
        st=costv + 0.05f*sB[g]*sRuC[g] + 0.02f*sB[g]*sRdC[g];
        const int o=b*2400 + g*T_ + t_own;
        out[o]=Pv;
        out[19200+o]=sRuC[g];
        out[38400+o]=sRdC[g];
        out[57600+o]=costv;
      }
      blockReduce2(st,dum0,sRed);
      if (tid==0) gstore64(&ST1[(b*T_+t_own)*16], pack(st,99u));
      if (t_own==0){
        if (tid==0) out[77824+b]=gam;
        float s1=0.f;
        if (tid<64){
          u64 xs = (lane<T_)? gload64(&ST1[(b*T_+lane)*16]) : pack(0.f,99u);
          while (unpackt(xs)!=99u){ __builtin_amdgcn_s_sleep(1); xs=gload64(&ST1[(b*T_+lane)*16]); }
          s1=unpackv(xs);
        }
        float pm=(tid<NSC)? sQn[tid] : 0.f;
        blockReduce2(pm,s1,sRed);
        if (tid==0) out[77832+b] = s1 + pm*INVN + epsv*gam;
      }
      break;
    }

    // ---- wave0: butterfly + weights + LS/SP + S-sums + early gamma ----
    if (w0){
#pragma unroll
      for (int off=32; off; off>>=1){ Qmax+=__shfl_xor(Qmax,off,64); Qmin+=__shfl_xor(Qmin,off,64); }
      float g1l=0.f,g2l=0.f,sgl=0.f;
#pragma unroll
      for (int h=0;h<2;++h){
        const int nn=lane+h*64;
        const float Qn=sQnP[nn]+sQnP[nn+128]+sQnP[nn+256]+sQnP[nn+384];
        const float m1=Qmax-gamma*sDM[nn], m2=Qmin-gamma*sDm[nn];
        const float inner=fmaxf(m1,m2), ph=fmaxf(Qn,inner);
        const float gQn=(Qn==ph?1.f:0.f)/((inner==ph)?2.f:1.f);
        const float gIn=(inner==ph?1.f:0.f)/((Qn==ph)?2.f:1.f);
        const float gm1=gIn*(m1==inner?1.f:0.f)/((m2==inner)?2.f:1.f);
        const float gm2=gIn*(m2==inner?1.f:0.f)/((m1==inner)?2.f:1.f);
        const float gq=gQn*INVN;
        sGQ[nn]=gq;
        g1l+=gm1; g2l+=gm2; sgl+=gm1*sDM[nn]+gm2*sDm[nn];
        const float r2=sS2[nn]+sLS[nn]-sSP[nn]-sOm[nn];
        const float r220=TWO_RHO*r2;
        sR220[nn]=r220;
        sLS[nn]=fmaxf(sLS[nn]-LR*(gq*VOLL+r220),0.f);
        sSP[nn]=fmaxf(sSP[nn]-LR*(gq*VOSP-r220),0.f);
      }
#pragma unroll
      for (int off=32; off; off>>=1){
        g1l+=__shfl_xor(g1l,off,64); g2l+=__shfl_xor(g2l,off,64); sgl+=__shfl_xor(sgl,off,64);
      }
      if (lane==0){ sScal[8]=g1l; sScal[9]=g2l; }
      if (t_own==0 && lane==0)
        gstore64(gamW, pack(fmaxf(gamma-LR*(epsv-INVN*sgl),0.f), tg2));
    }
    __syncthreads();   // barrier B

    // ---- pass A (7 waves) CONCURRENT WITH pass B + qs publish (wave1) ----
    if (pA){
      const float gqA=sGQ[lane],    r220A=sR220[lane];
      const float gqB=sGQ[lane+64], r220B=sR220[lane+64];
      float qvA=0.f,qvB=0.f,svA=0.f,svB=0.f;
#pragma unroll
      for (int j=0;j<GMAX;++j){
        if (j<gcnt){
          const int g=gbase+j;
          const float bg=sB[g];
          const float rtu=2.f*bg, rtd=0.5f*bg;
          const float ru=sRuC[g], rd=sRdC[g];
          const float r7A=fmaxf(duA[j]-ru,0.f), r8A=fmaxf(ddA[j]-rd,0.f);
          const float r7B=fmaxf(duB[j]-ru,0.f), r8B=fmaxf(ddB[j]-rd,0.f);
          duA[j]=fmaxf(duA[j]-LR*(gqA*rtu+(r220A+TWO_RHO*r7A)),0.f);
          ddA[j]=fmaxf(ddA[j]-LR*(gqA*rtd+(TWO_RHO*r8A-r220A)),0.f);
          duB[j]=fmaxf(duB[j]-LR*(gqB*rtu+(r220B+TWO_RHO*r7B)),0.f);
          ddB[j]=fmaxf(ddB[j]-LR*(gqB*rtd+(TWO_RHO*r8B-r220B)),0.f);
          qvA+=rtu*duA[j]+rtd*ddA[j];  svA+=duA[j]-ddA[j];
          qvB+=rtu*duB[j]+rtd*ddB[j];  svB+=duB[j]-ddB[j];
        }
      }
      sQp[lane*9+wave]=qvA;      sSp[lane*9+wave]=svA;
      sQp[(lane+64)*9+wave]=qvB; sSp[(lane+64)*9+wave]=svB;
    } else {
      // wave1: pass B (deps: consume + barrier B only — NOT pass A)
      const float r3=__shfl(r3reg,0,64), r4=__shfl(r4reg,0,64), rP=__shfl(rPreg,0,64);
      const float S1s=sScal[8], S2s=sScal[9];
      float pQx=0.f,pQn2=0.f,pr3=0.f,pr4=0.f,pP=0.f;
#pragma unroll
      for (int i=0;i<2;++i){
        if (i==0 || hasG1){
          const int g = lane + i*64;
          const float rupS=sAccU[g], rdnS=sAccD[g];
          const float Pold=sP[g], ru=sRuC[g], rd=sRdC[g];
          const float duMo=duMr[i], ddMo=ddMr[i], dumo=dumr[i], ddmo=ddmr[i];
          const float r5 =fmaxf(Pold+ru-sPmax[g],0.f);
          const float r6 =fmaxf(sPmin[g]-Pold+rd,0.f);
          const float r9 =fmaxf(duMo-ru,0.f), r10=fmaxf(ddMo-rd,0.f);
          const float r11=fmaxf(dumo-ru,0.f), r12=fmaxf(ddmo-rd,0.f);
          const float rampg=sPmax[g];
          float gP=sB[g]+TWO_RHO*(rP+r5-r6);
          if (t_own>0){
            const float dp=Pold-unpackv(i==0?xm0:xm1);
            gP+=TWO_RHO*fmaxf(fabsf(dp)-rampg,0.f)*(dp>=0.f?1.f:-1.f);
          }
          if (t_own<T_-1){
            const float dq=unpackv(i==0?xp0:xp1)-Pold;
            gP-=TWO_RHO*fmaxf(fabsf(dq)-rampg,0.f)*(dq>=0.f?1.f:-1.f);
          }
          const float Pn=fminf(fmaxf(Pold-LR*gP,sPmin[g]),sPmax[g]);
          sP[g]=Pn; gstore64(&ppW[g], pack(Pn,tg2));
          const float rtuB=2.f*sB[g], rtdB=0.5f*sB[g];
          sRuN[g]=fmaxf(ru-LR*(0.05f*sB[g]+TWO_RHO*(r5-rupS-r9-r11)),0.f);
          sRdN[g]=fmaxf(rd-LR*(0.02f*sB[g]+TWO_RHO*(r6-rdnS-r10-r12)),0.f);
          const float duMn=fmaxf(duMo-LR*(INVN*S1s*rtuB+TWO_RHO*( r3+r9 )),0.f);
          const float ddMn=fmaxf(ddMo-LR*(INVN*S1s*rtdB+TWO_RHO*(-r3+r10)),0.f);
          const float dumn=fmaxf(dumo-LR*(INVN*S2s*rtuB+TWO_RHO*( r4+r11)),0.f);
          const float ddmn=fmaxf(ddmo-LR*(INVN*S2s*rtdB+TWO_RHO*(-r4+r12)),0.f);
          duMr[i]=duMn; ddMr[i]=ddMn; dumr[i]=dumn; ddmr[i]=ddmn;
          pQx+=rtuB*duMn+rtdB*ddMn; pQn2+=rtuB*dumn+rtdB*ddmn;
          pr3+=duMn-ddMn; pr4+=dumn-ddmn; pP+=Pn;
        }
      }
#pragma unroll
      for (int off=32; off; off>>=1){
        pQx+=__shfl_down(pQx,off,64);  pQn2+=__shfl_down(pQn2,off,64);
        pr3+=__shfl_down(pr3,off,64);  pr4+=__shfl_down(pr4,off,64);
        pP +=__shfl_down(pP,off,64);
      }
      if (lane==0){
        const float LSMn=fmaxf(lsm-LR*(INVN*S1s*VOLL+TWO_RHO*r3),0.f);
        const float SPMn=fmaxf(spm-LR*(INVN*S1s*VOSP-TWO_RHO*r3),0.f);
        const float LSmn=fmaxf(lsn-LR*(INVN*S2s*VOLL+TWO_RHO*r4),0.f);
        const float SPmn=fmaxf(spn-LR*(INVN*S2s*VOSP-TWO_RHO*r4),0.f);
        lsm=LSMn; spm=SPMn; lsn=LSmn; spn=SPmn;
        gstore64(&qsW[0], pack(pQx + VOLL*LSMn + VOSP*SPMn, tg2));   // qs lands EARLY
        gstore64(&qsW[1], pack(pQn2 + VOLL*LSmn + VOSP*SPmn, tg2));
        r3reg=pr3 + LSMn - SPMn - omaxT;
        r4reg=pr4 + LSmn - SPmn - ominT;
        rPreg=pP - fctT;
      }
    }
    __syncthreads();   // barrier C (last barrier of the iteration)

    // ---- combine (waves 4-5) + shadow (pass-A waves) — slack side ----
    if (tid>=256 && tid<384){
      const int nn=tid-256;
      float q=0.f,s=0.f;
#pragma unroll
      for (int w=0;w<8;++w){ q+=sQp[nn*9+w]; s+=sSp[nn*9+w]; }
      sS2[nn]=s;
      q += VOLL*sLS[nn]+VOSP*sSP[nn];
      gstore64(&qnpW[nn], pack(q,tg2));
    }
    if (pA){
#pragma unroll
      for (int j=0;j<GMAX;++j){
        if (j<gcnt){
          const int g=gbase+j;
          const float ru=sRuN[g], rd=sRdN[g];   // NEW Ru/Rd (pass B done at barrier C)
          float aU=fmaxf(duA[j]-ru,0.f)+fmaxf(duB[j]-ru,0.f);
          float aD=fmaxf(ddA[j]-rd,0.f)+fmaxf(ddB[j]-rd,0.f);
#pragma unroll
          for (int off=32; off; off>>=1){ aU+=__shfl_xor(aU,off,64); aD+=__shfl_xor(aD,off,64); }
          if (lane==0){ sAccU[g]=aU; sAccD[g]=aD; }
        }
      }
    }
  }
}

extern "C" void kernel_launch(void* const* d_in, const int* in_sizes, int n_in,
                              void* d_out, int out_size, void* d_ws, size_t ws_size,
                              hipStream_t stream) {
  const float* forecast = (const float*)d_in[0];
  const float* omega    = (const float*)d_in[1];
  const float* omin     = (const float*)d_in[2];
  const float* omax     = (const float*)d_in[3];
  const float* eps      = (const float*)d_in[4];
  const float* pmin     = (const float*)d_in[5];
  const float* pmax     = (const float*)d_in[6];
  const float* bG       = (const float*)d_in[7];
  const float* cG       = (const float*)d_in[8];
  float* out = (float*)d_out;
  float* ws  = (float*)d_ws;
  void* args[] = { &forecast, &omega, &omin, &omax, &eps, &pmin, &pmax, &bG, &cG, &out, &ws };
  hipLaunchCooperativeKernel((const void*)dro_kernel, dim3(NBLK), dim3(NTHR),
                             args, 0, stream);
}